// Round 1
// 249.153 us; speedup vs baseline: 1.0003x; 1.0003x over previous
//
#include <hip/hip_runtime.h>

// CausalAttention: B=4, S=2048, D=1024, single head over full D.
// R5: all three GEMMs move to a double-buffered BK=64 core with counted
// vmcnt (T3 depth-1 + T4): stage tile t+1 BEFORE computing tile t, raw
// s_barrier + s_waitcnt vmcnt(8) instead of __syncthreads' vmcnt(0) drain.
// Only the epilogue tile drains vmcnt to 0. LDS 64 KB/block (2 blocks/CU).
// Softmax stays fused into qk (exp + row-sum atomics, packed-tri P).

typedef __attribute__((ext_vector_type(8))) _Float16 f16x8;
typedef __attribute__((ext_vector_type(4))) _Float16 f16x4;
typedef __attribute__((ext_vector_type(4))) float f32x4;

#define NB   4
#define SEQ  2048
#define DIM  1024
#define SCL  0.03125f   // 1/sqrt(1024)
#define PBATCH (136 * 16384)   // packed P elems per batch (tri(16) tiles)

__device__ __forceinline__ void gll16(const _Float16* g, _Float16* l) {
  __builtin_amdgcn_global_load_lds(
      (__attribute__((address_space(1))) void*)(g),
      (__attribute__((address_space(3))) void*)(l), 16, 0, 0);
}

// ---------------- BK=64 double-buffered core (qkv, qk, pv) ----------------
// As/Bs [2][128][64] fp16 (32 KB each). Row = 128 B = all 32 banks, so
// swizzle chunk' = chunk ^ (row&7) over the 8 16B-chunks/row -> 2-way (free).
// Staging: 4 gll16 lines per operand per tile; thread t covers
//   row = (4*line+wv)*8 + (ln>>3), slot chunk = ln&7, src chunk = slot^(ln>>3).
// Pipeline per K-tile:
//   stage(next half)  -> 8 gll16 in flight
//   s_waitcnt vmcnt(8) -> previous tile's loads landed (only those)
//   s_barrier          -> all waves' previous loads landed
//   ds_read + 32 MFMA  (compiler inserts lgkm waits)
//   s_barrier          -> all waves done reading this half
__device__ __forceinline__ void gemm_core64_db(
    const _Float16* __restrict__ A, int lda,
    const _Float16* __restrict__ Bm, int ldb,
    int K, _Float16* As, _Float16* Bs, f32x4 acc[4][4])
{
  const int t    = threadIdx.x;
  const int wv   = t >> 6;
  const int ln   = t & 63;
  const int lr   = ln & 15;
  const int lq   = ln >> 4;
  const int rsub = ln >> 3;                       // 0..7
  const int colb = (((ln & 7) ^ rsub) * 8);       // swizzled source chunk

  const _Float16* ga[4]; const _Float16* gb[4];
  _Float16* dA[4]; _Float16* dB[4];
#pragma unroll
  for (int l = 0; l < 4; ++l) {
    const int row = (4 * l + wv) * 8 + rsub;
    ga[l] = A  + row * lda + colb;
    gb[l] = Bm + row * ldb + colb;
    dA[l] = As + (4 * l + wv) * 512;              // 512 elems = 1 KB per line
    dB[l] = Bs + (4 * l + wv) * 512;
  }

  // fragment read: row = wm*64+mi*16+lr (row&7 == lr&7); k-chunk = ks*4+lq
  const int swzr = lr & 7;
  const int ra = (((wv & 1) * 64) + lr) * 64;
  const int rb = (((wv >> 1) * 64) + lr) * 64;
  const int c0 = ((0 * 4 + lq) ^ swzr) * 8;
  const int c1 = ((1 * 4 + lq) ^ swzr) * 8;

  auto compute = [&](int half) {
    const _Float16* pa = As + half * 8192 + ra;
    const _Float16* pb = Bs + half * 8192 + rb;
    f16x8 af[4][2], bf[4][2];
#pragma unroll
    for (int mi = 0; mi < 4; ++mi) {
      af[mi][0] = *(const f16x8*)(pa + mi * 1024 + c0);
      af[mi][1] = *(const f16x8*)(pa + mi * 1024 + c1);
    }
#pragma unroll
    for (int ni = 0; ni < 4; ++ni) {
      bf[ni][0] = *(const f16x8*)(pb + ni * 1024 + c0);
      bf[ni][1] = *(const f16x8*)(pb + ni * 1024 + c1);
    }
#pragma unroll
    for (int ks = 0; ks < 2; ++ks)
#pragma unroll
      for (int mi = 0; mi < 4; ++mi)
#pragma unroll
        for (int ni = 0; ni < 4; ++ni)
          acc[mi][ni] = __builtin_amdgcn_mfma_f32_16x16x32_f16(
              af[mi][ks], bf[ni][ks], acc[mi][ni], 0, 0, 0);
  };

  // prologue: stage tile 0 into half 0
#pragma unroll
  for (int l = 0; l < 4; ++l) gll16(ga[l], dA[l]);
#pragma unroll
  for (int l = 0; l < 4; ++l) gll16(gb[l], dB[l]);

  int cur = 0;
  for (int k0 = 64; k0 < K; k0 += 64) {
    const int nxt = cur ^ 1;
    // stage next tile into the other half (prev iter's barrier made it safe)
#pragma unroll
    for (int l = 0; l < 4; ++l) gll16(ga[l] + k0, dA[l] + nxt * 8192);
#pragma unroll
    for (int l = 0; l < 4; ++l) gll16(gb[l] + k0, dB[l] + nxt * 8192);
    asm volatile("s_waitcnt vmcnt(8)" ::: "memory");  // prev tile landed
    __builtin_amdgcn_s_barrier();
    compute(cur);
    __builtin_amdgcn_s_barrier();   // lgkm already drained by MFMA consumption
    cur = nxt;
  }
  // epilogue: final tile (only full drain in the loop)
  asm volatile("s_waitcnt vmcnt(0)" ::: "memory");
  __builtin_amdgcn_s_barrier();
  compute(cur);
}

// one kernel converts x, Wq, Wk, Wv (blockIdx.y selects segment)
__global__ __launch_bounds__(256) void cvt_all(
    const float* __restrict__ x, const float* __restrict__ Wq,
    const float* __restrict__ Wk, const float* __restrict__ Wv,
    _Float16* __restrict__ xb, _Float16* __restrict__ Wb)
{
  const float* src; _Float16* dst; int n;
  const int M1 = 1024 * 1024;
  switch (blockIdx.y) {
    case 0: src = x;  dst = xb;          n = NB * SEQ * DIM; break;
    case 1: src = Wq; dst = Wb;          n = M1; break;
    case 2: src = Wk; dst = Wb + M1;     n = M1; break;
    default: src = Wv; dst = Wb + 2*M1;  n = M1; break;
  }
  int i = (blockIdx.x * 256 + threadIdx.x) * 4;
  const int stride = gridDim.x * 256 * 4;
  for (; i < n; i += stride) {
    const float4 v = *(const float4*)(src + i);
    f16x4 o;
    o.x = (_Float16)v.x; o.y = (_Float16)v.y; o.z = (_Float16)v.z; o.w = (_Float16)v.w;
    *(f16x4*)(dst + i) = o;
  }
}

// z=0: Q -> Qb; z=1: K -> Kb; z=2: V -> Vt [b][d][s] (transposed)
__global__ __launch_bounds__(256, 2) void qkv_gemm(
    const _Float16* __restrict__ xb, const _Float16* __restrict__ Wb,
    const float* __restrict__ bq, const float* __restrict__ bk,
    const float* __restrict__ bv,
    _Float16* __restrict__ Qb, _Float16* __restrict__ Kb, _Float16* __restrict__ Vt)
{
  __shared__ _Float16 As[16384];
  __shared__ _Float16 Bs[16384];
  const int m0 = blockIdx.x * 128;
  const int n0 = blockIdx.y * 128;
  const int z  = blockIdx.z;
  f32x4 acc[4][4];
#pragma unroll
  for (int mi = 0; mi < 4; ++mi)
#pragma unroll
    for (int ni = 0; ni < 4; ++ni) acc[mi][ni] = {0.f, 0.f, 0.f, 0.f};

  gemm_core64_db(xb + (size_t)m0 * DIM, DIM,
                 Wb + (size_t)z * DIM * DIM + (size_t)n0 * DIM, DIM,
                 DIM, As, Bs, acc);

  const int t = threadIdx.x, wv = t >> 6, ln = t & 63, lr = ln & 15, lq = ln >> 4;
  const int wm = wv & 1, wn = wv >> 1;
  const float* bias = (z == 0) ? bq : (z == 1) ? bk : bv;
  if (z < 2) {
    _Float16* O = (z == 0) ? Qb : Kb;
#pragma unroll
    for (int ni = 0; ni < 4; ++ni) {
      const int col = n0 + wn * 64 + ni * 16 + lr;
      const float bb = bias[col];
#pragma unroll
      for (int mi = 0; mi < 4; ++mi) {
        const int r0 = m0 + wm * 64 + mi * 16 + lq * 4;
#pragma unroll
        for (int r = 0; r < 4; ++r)
          O[(size_t)(r0 + r) * DIM + col] = (_Float16)(acc[mi][ni][r] + bb);
      }
    }
  } else {
#pragma unroll
    for (int ni = 0; ni < 4; ++ni) {
      const int col = n0 + wn * 64 + ni * 16 + lr;
      const float bb = bias[col];
#pragma unroll
      for (int mi = 0; mi < 4; ++mi) {
        const int r0 = m0 + wm * 64 + mi * 16 + lq * 4;
        const int b = r0 >> 11, s = r0 & 2047;
        f16x4 pk;
#pragma unroll
        for (int r = 0; r < 4; ++r) pk[r] = (_Float16)(acc[mi][ni][r] + bb);
        *(f16x4*)(Vt + (size_t)b * DIM * SEQ + (size_t)col * SEQ + s) = pk;
      }
    }
  }
}

// Fused QK^T + exp + row-sum. Grid x = 136 lower-tri tiles, y = batch.
__global__ __launch_bounds__(256, 2) void qk_gemm(
    const _Float16* __restrict__ Qb, const _Float16* __restrict__ Kb,
    _Float16* __restrict__ Pm, float* __restrict__ lsum)
{
  const int idx = blockIdx.x;
  int qt = 0;
  while ((qt + 1) * (qt + 2) / 2 <= idx) ++qt;
  const int kt = idx - qt * (qt + 1) / 2;
  const int q0 = qt * 128, k0 = kt * 128, b = blockIdx.y;

  __shared__ _Float16 As[16384];
  __shared__ _Float16 Bs[16384];
  f32x4 acc[4][4];
#pragma unroll
  for (int mi = 0; mi < 4; ++mi)
#pragma unroll
    for (int ni = 0; ni < 4; ++ni) acc[mi][ni] = {0.f, 0.f, 0.f, 0.f};

  const _Float16* Qp = Qb + (size_t)b * SEQ * DIM + (size_t)q0 * DIM;
  const _Float16* Kp = Kb + (size_t)b * SEQ * DIM + (size_t)k0 * DIM;
  gemm_core64_db(Qp, DIM, Kp, DIM, DIM, As, Bs, acc);

  const int t = threadIdx.x, wv = t >> 6, ln = t & 63, lr = ln & 15, lq = ln >> 4;
  const int wm = wv & 1, wn = wv >> 1;
  const int ldp = (qt + 1) * 128;
  _Float16* scr = Pm + (size_t)b * PBATCH + (size_t)(qt * (qt + 1) / 2) * 16384;
  float* lrow = lsum + b * SEQ;

  float es[4][4];
#pragma unroll
  for (int mi = 0; mi < 4; ++mi)
#pragma unroll
    for (int r = 0; r < 4; ++r) es[mi][r] = 0.f;

#pragma unroll
  for (int ni = 0; ni < 4; ++ni) {
    const int col = k0 + wn * 64 + ni * 16 + lr;
#pragma unroll
    for (int mi = 0; mi < 4; ++mi) {
      const int r0 = q0 + wm * 64 + mi * 16 + lq * 4;
#pragma unroll
      for (int r = 0; r < 4; ++r) {
        const int row = r0 + r;
        const float s = acc[mi][ni][r] * SCL;
        const float e = (col <= row) ? __expf(fminf(s, 10.f)) : 0.f;
        scr[(size_t)(row - q0) * ldp + col] = (_Float16)e;
        es[mi][r] += e;
      }
    }
  }
#pragma unroll
  for (int mi = 0; mi < 4; ++mi)
#pragma unroll
    for (int r = 0; r < 4; ++r) {
      float v = es[mi][r];
#pragma unroll
      for (int off = 1; off < 16; off <<= 1) v += __shfl_xor(v, off, 64);
      if (lr == 0) {
        const int row = q0 + wm * 64 + mi * 16 + lq * 4 + r;
        atomicAdd(&lrow[row], v);
      }
    }
}

// out[b][q][d] = (sum_k e[q][k] * Vt[b][d][k]) / l[b][q]; qt big-first.
__global__ __launch_bounds__(256, 2) void pv_gemm(
    const _Float16* __restrict__ Pm, const _Float16* __restrict__ Vt,
    const float* __restrict__ lsum, float* __restrict__ out)
{
  __shared__ _Float16 As[16384];
  __shared__ _Float16 Bs[16384];
  const int qt = 15 - blockIdx.x;
  const int q0 = qt * 128;
  const int d0 = blockIdx.y * 128;
  const int b  = blockIdx.z;
  const int K  = (qt + 1) * 128;
  f32x4 acc[4][4];
#pragma unroll
  for (int mi = 0; mi < 4; ++mi)
#pragma unroll
    for (int ni = 0; ni < 4; ++ni) acc[mi][ni] = {0.f, 0.f, 0.f, 0.f};

  const _Float16* Pp = Pm + (size_t)b * PBATCH + (size_t)(qt * (qt + 1) / 2) * 16384;
  const _Float16* Vp = Vt + (size_t)b * DIM * SEQ + (size_t)d0 * SEQ;
  gemm_core64_db(Pp, K, Vp, SEQ, K, As, Bs, acc);

  const int t = threadIdx.x, wv = t >> 6, ln = t & 63, lr = ln & 15, lq = ln >> 4;
  const int wm = wv & 1, wn = wv >> 1;
  float* O = out + (size_t)b * SEQ * DIM;
  const float* lrow = lsum + b * SEQ;
#pragma unroll
  for (int mi = 0; mi < 4; ++mi) {
    const int r0 = q0 + wm * 64 + mi * 16 + lq * 4;
    const float4 lv = *(const float4*)(lrow + r0);
    const float inv[4] = {1.f / lv.x, 1.f / lv.y, 1.f / lv.z, 1.f / lv.w};
#pragma unroll
    for (int ni = 0; ni < 4; ++ni) {
      const int col = d0 + wn * 64 + ni * 16 + lr;
#pragma unroll
      for (int r = 0; r < 4; ++r)
        O[(size_t)(r0 + r) * DIM + col] = acc[mi][ni][r] * inv[r];
    }
  }
}

extern "C" void kernel_launch(void* const* d_in, const int* in_sizes, int n_in,
                              void* d_out, int out_size, void* d_ws, size_t ws_size,
                              hipStream_t stream) {
  const float* x  = (const float*)d_in[0];
  const float* Wq = (const float*)d_in[1];
  const float* bq = (const float*)d_in[2];
  const float* Wk = (const float*)d_in[3];
  const float* bk = (const float*)d_in[4];
  const float* Wv = (const float*)d_in[5];
  const float* bv = (const float*)d_in[6];
  float* out = (float*)d_out;

  _Float16* w16 = (_Float16*)d_ws;
  const size_t M1 = (size_t)1024 * 1024;
  _Float16* Qb = w16;                 //  0M .. 8M el (16 MB)
  _Float16* Kb = w16 + 8 * M1;        //  8M .. 16M
  _Float16* Vt = w16 + 16 * M1;       // 16M .. 24M  (V transposed [b][d][s])
  _Float16* xb = w16 + 24 * M1;       // 24M .. 32M  (dead after qkv_gemm)
  _Float16* Wb = w16 + 32 * M1;       // 32M .. 35M  (dead after qkv_gemm)
  _Float16* Pm = w16 + 24 * M1;       // packed tri P (17.8 MB), aliases xb
  float*    lsum = (float*)(w16 + 34 * M1);  // 32 KB row sums

  hipMemsetAsync(lsum, 0, NB * SEQ * sizeof(float), stream);
  cvt_all<<<dim3(512, 4), 256, 0, stream>>>(x, Wq, Wk, Wv, xb, Wb);
  qkv_gemm<<<dim3(64, 8, 3), 256, 0, stream>>>(xb, Wb, bq, bk, bv, Qb, Kb, Vt);
  qk_gemm<<<dim3(136, NB), 256, 0, stream>>>(Qb, Kb, Pm, lsum);
  pv_gemm<<<dim3(16, 8, NB), 256, 0, stream>>>(Pm, Vt, lsum, out);
}